// Round 1
// baseline (2851.497 us; speedup 1.0000x reference)
//
#include <hip/hip_runtime.h>
#include <cstdint>
#include <cstddef>

// Problem constants (fixed by reference): B=16, N=M=2048, eps=0.05, 50 iters.
constexpr int B = 16, N = 2048, M = 2048;
constexpr int MAX_ITER = 50;
// exp(-cost/eps) = exp2(cost * C2), C2 = -(1/0.05) * log2(e)
#define C2 (-28.853900817779268f)

constexpr int CHUNKS = 64;                     // col-pass row chunks per batch
constexpr int ROWS_PER_CHUNK = N / CHUNKS;     // 32
constexpr int ROWS_WG = 16;                    // u-pass rows per workgroup (4 waves x 4 rows)

__device__ __forceinline__ unsigned short f2bf(float f) {
  union { float f; unsigned u; } x; x.f = f;
  unsigned r = x.u + 0x7fffu + ((x.u >> 16) & 1u);   // RNE; inputs are finite positives
  return (unsigned short)(r >> 16);
}
__device__ __forceinline__ float bflo(unsigned w) { union { unsigned u; float f; } x; x.u = w << 16; return x.f; }
__device__ __forceinline__ float bfhi(unsigned w) { union { unsigned u; float f; } x; x.u = w & 0xffff0000u; return x.f; }

// ---------------- init: K = bf16(exp(-cost/eps)), v = 1 ----------------
__global__ __launch_bounds__(256) void init_K(const float* __restrict__ cost,
                                              uint4* __restrict__ K,
                                              float* __restrict__ v) {
  unsigned gid = blockIdx.x * 256u + threadIdx.x;        // 8,388,608 threads, 8 elems each
  const float4* c4 = (const float4*)cost;
  float4 a = c4[(size_t)gid * 2];
  float4 b = c4[(size_t)gid * 2 + 1];
  float k0 = exp2f(a.x * C2), k1 = exp2f(a.y * C2), k2 = exp2f(a.z * C2), k3 = exp2f(a.w * C2);
  float k4 = exp2f(b.x * C2), k5 = exp2f(b.y * C2), k6 = exp2f(b.z * C2), k7 = exp2f(b.w * C2);
  uint4 w;
  w.x = (unsigned)f2bf(k0) | ((unsigned)f2bf(k1) << 16);
  w.y = (unsigned)f2bf(k2) | ((unsigned)f2bf(k3) << 16);
  w.z = (unsigned)f2bf(k4) | ((unsigned)f2bf(k5) << 16);
  w.w = (unsigned)f2bf(k6) | ((unsigned)f2bf(k7) << 16);
  K[gid] = w;
  if (gid < (unsigned)(B * M)) v[gid] = 1.0f;
}

__global__ __launch_bounds__(256) void init_v_only(float* __restrict__ v) {
  unsigned g = blockIdx.x * 256u + threadIdx.x;
  if (g < (unsigned)(B * M)) v[g] = 1.0f;
}

// ---------------- u-pass: u[b,n] = (r[b,n]+1e-12) / sum_m K[b,n,m]*v[b,m] ----------------
template <bool BF16K>
__global__ __launch_bounds__(256) void u_pass(const void* __restrict__ Kv_,
                                              const float* __restrict__ cost,
                                              const float* __restrict__ r,
                                              const float* __restrict__ v,
                                              float* __restrict__ u) {
  const int b = blockIdx.y;
  const int row0 = blockIdx.x * ROWS_WG;
  const int t = threadIdx.x;
  __shared__ float vs[M];
  const float4* vv = (const float4*)(v + (size_t)b * M);
  ((float4*)vs)[t]       = vv[t];
  ((float4*)vs)[t + 256] = vv[t + 256];
  __syncthreads();
  const int wave = t >> 6, lane = t & 63;
  // Preload this lane's 32 v values into registers, reused across 4 rows.
  float vreg[32];
#pragma unroll
  for (int it = 0; it < 4; ++it) {
    float4 a = ((const float4*)vs)[it * 128 + lane * 2];
    float4 c = ((const float4*)vs)[it * 128 + lane * 2 + 1];
    vreg[it * 8 + 0] = a.x; vreg[it * 8 + 1] = a.y; vreg[it * 8 + 2] = a.z; vreg[it * 8 + 3] = a.w;
    vreg[it * 8 + 4] = c.x; vreg[it * 8 + 5] = c.y; vreg[it * 8 + 6] = c.z; vreg[it * 8 + 7] = c.w;
  }
#pragma unroll
  for (int rr = 0; rr < ROWS_WG / 4; ++rr) {
    const int row = row0 + wave * (ROWS_WG / 4) + rr;
    float acc = 0.f;
    if (BF16K) {
      const uint4* Kr = (const uint4*)Kv_ + (size_t)(b * N + row) * (M / 8);
#pragma unroll
      for (int it = 0; it < 4; ++it) {
        uint4 w = Kr[it * 64 + lane];
        acc += bflo(w.x) * vreg[it * 8 + 0] + bfhi(w.x) * vreg[it * 8 + 1]
             + bflo(w.y) * vreg[it * 8 + 2] + bfhi(w.y) * vreg[it * 8 + 3]
             + bflo(w.z) * vreg[it * 8 + 4] + bfhi(w.z) * vreg[it * 8 + 5]
             + bflo(w.w) * vreg[it * 8 + 6] + bfhi(w.w) * vreg[it * 8 + 7];
      }
    } else {
      const float4* Cr = (const float4*)(cost + (size_t)(b * N + row) * M);
#pragma unroll
      for (int it = 0; it < 4; ++it) {
        float4 a = Cr[it * 128 + lane * 2];
        float4 c = Cr[it * 128 + lane * 2 + 1];
        acc += exp2f(a.x * C2) * vreg[it * 8 + 0] + exp2f(a.y * C2) * vreg[it * 8 + 1]
             + exp2f(a.z * C2) * vreg[it * 8 + 2] + exp2f(a.w * C2) * vreg[it * 8 + 3]
             + exp2f(c.x * C2) * vreg[it * 8 + 4] + exp2f(c.y * C2) * vreg[it * 8 + 5]
             + exp2f(c.z * C2) * vreg[it * 8 + 6] + exp2f(c.w * C2) * vreg[it * 8 + 7];
      }
    }
#pragma unroll
    for (int off = 32; off; off >>= 1) acc += __shfl_xor(acc, off, 64);
    if (lane == 0) u[b * N + row] = (r[b * N + row] + 1e-12f) / acc;
  }
}

// ---------------- col-pass: partial[b,chunk,m] = sum_{n in chunk} K[b,n,m]*u[b,n] ----------------
template <bool BF16K>
__global__ __launch_bounds__(256) void col_pass(const void* __restrict__ Kv_,
                                                const float* __restrict__ cost,
                                                const float* __restrict__ u,
                                                float* __restrict__ part) {
  const int b = blockIdx.y, chunk = blockIdx.x;
  const int n0 = chunk * ROWS_PER_CHUNK;
  const int t = threadIdx.x;
  __shared__ float us[ROWS_PER_CHUNK];
  if (t < ROWS_PER_CHUNK) us[t] = u[b * N + n0 + t];
  __syncthreads();
  float acc[8] = {0, 0, 0, 0, 0, 0, 0, 0};
  if (BF16K) {
    const uint4* Kb = (const uint4*)Kv_ + (size_t)(b * N + n0) * (M / 8) + t;
#pragma unroll 4
    for (int n = 0; n < ROWS_PER_CHUNK; ++n) {
      uint4 w = Kb[(size_t)n * (M / 8)];
      float uval = us[n];
      acc[0] += bflo(w.x) * uval; acc[1] += bfhi(w.x) * uval;
      acc[2] += bflo(w.y) * uval; acc[3] += bfhi(w.y) * uval;
      acc[4] += bflo(w.z) * uval; acc[5] += bfhi(w.z) * uval;
      acc[6] += bflo(w.w) * uval; acc[7] += bfhi(w.w) * uval;
    }
  } else {
    const float4* Cb = (const float4*)(cost + (size_t)(b * N + n0) * M) + t * 2;
#pragma unroll 2
    for (int n = 0; n < ROWS_PER_CHUNK; ++n) {
      float4 a = Cb[(size_t)n * (M / 4)];
      float4 c = Cb[(size_t)n * (M / 4) + 1];
      float uval = us[n];
      acc[0] += exp2f(a.x * C2) * uval; acc[1] += exp2f(a.y * C2) * uval;
      acc[2] += exp2f(a.z * C2) * uval; acc[3] += exp2f(a.w * C2) * uval;
      acc[4] += exp2f(c.x * C2) * uval; acc[5] += exp2f(c.y * C2) * uval;
      acc[6] += exp2f(c.z * C2) * uval; acc[7] += exp2f(c.w * C2) * uval;
    }
  }
  float4* P = (float4*)(part + (size_t)(b * CHUNKS + chunk) * M) + t * 2;
  float4 o0; o0.x = acc[0]; o0.y = acc[1]; o0.z = acc[2]; o0.w = acc[3];
  float4 o1; o1.x = acc[4]; o1.y = acc[5]; o1.z = acc[6]; o1.w = acc[7];
  P[0] = o0; P[1] = o1;
}

// ---------------- v-finalize: v[b,m] = (c[b,m]+1e-12) / sum_chunks partial ----------------
__global__ __launch_bounds__(256) void v_fin(const float* __restrict__ part,
                                             const float* __restrict__ c,
                                             float* __restrict__ v) {
  const int g = blockIdx.x * 256 + threadIdx.x;   // 0..B*M-1
  const int b = g >> 11, m = g & (M - 1);
  float s = 0.f;
#pragma unroll 8
  for (int ch = 0; ch < CHUNKS; ++ch) s += part[(size_t)(b * CHUNKS + ch) * M + m];
  v[g] = (c[g] + 1e-12f) / s;
}

// ---------------- final: T = u[n] * exp(-cost/eps) * v[m], exact from fp32 cost ----------------
__global__ __launch_bounds__(256) void final_T(const float* __restrict__ cost,
                                               const float* __restrict__ u,
                                               const float* __restrict__ v,
                                               float* __restrict__ out) {
  const int b = blockIdx.z, n = blockIdx.y;
  const int m4 = blockIdx.x * 256 + threadIdx.x;  // 0..M/4-1
  const float un = u[b * N + n];
  float4 vv = ((const float4*)(v + (size_t)b * M))[m4];
  const size_t off = ((size_t)(b * N + n) * M) / 4 + m4;
  float4 cc = ((const float4*)cost)[off];
  float4 o;
  o.x = un * vv.x * exp2f(cc.x * C2);
  o.y = un * vv.y * exp2f(cc.y * C2);
  o.z = un * vv.z * exp2f(cc.z * C2);
  o.w = un * vv.w * exp2f(cc.w * C2);
  ((float4*)out)[off] = o;
}

extern "C" void kernel_launch(void* const* d_in, const int* in_sizes, int n_in,
                              void* d_out, int out_size, void* d_ws, size_t ws_size,
                              hipStream_t stream) {
  const float* cost = (const float*)d_in[0];
  const float* r    = (const float*)d_in[1];
  const float* c    = (const float*)d_in[2];
  float* out        = (float*)d_out;
  char* ws          = (char*)d_ws;

  const size_t K_bytes    = (size_t)B * N * M * 2;           // 128 MiB bf16 K
  const size_t u_bytes    = (size_t)B * N * 4;
  const size_t v_bytes    = (size_t)B * M * 4;
  const size_t part_bytes = (size_t)B * CHUNKS * M * 4;      // 8 MiB
  const size_t need_main  = K_bytes + u_bytes + v_bytes + part_bytes;
  const bool useK = (ws_size >= need_main);                  // ws_size constant across calls

  void* K; float *u, *v, *part;
  if (useK) {
    K = ws;
    u = (float*)(ws + K_bytes);
  } else {
    K = nullptr;
    u = (float*)ws;
  }
  v = u + (size_t)B * N;
  part = v + (size_t)B * M;

  if (useK) {
    init_K<<<dim3((B * (size_t)N * M) / (256 * 8)), 256, 0, stream>>>(cost, (uint4*)K, v);
  } else {
    init_v_only<<<dim3((B * M + 255) / 256), 256, 0, stream>>>(v);
  }

  for (int it = 0; it < MAX_ITER; ++it) {
    if (useK) {
      u_pass<true><<<dim3(N / ROWS_WG, B), 256, 0, stream>>>(K, cost, r, v, u);
      col_pass<true><<<dim3(CHUNKS, B), 256, 0, stream>>>(K, cost, u, part);
    } else {
      u_pass<false><<<dim3(N / ROWS_WG, B), 256, 0, stream>>>(nullptr, cost, r, v, u);
      col_pass<false><<<dim3(CHUNKS, B), 256, 0, stream>>>(nullptr, cost, u, part);
    }
    v_fin<<<dim3(B * M / 256), 256, 0, stream>>>(part, c, v);
  }

  final_T<<<dim3(M / 1024, N, B), 256, 0, stream>>>(cost, u, v, out);
}

// Round 2
// 2733.838 us; speedup vs baseline: 1.0430x; 1.0430x over previous
//
#include <hip/hip_runtime.h>
#include <cstdint>
#include <cstddef>

// Problem constants (fixed by reference): B=16, N=M=2048, eps=0.05, 50 iters.
constexpr int B = 16, N = 2048, M = 2048;
constexpr int MAX_ITER = 50;
// exp(-cost/eps) = exp2(cost * C2), C2 = -(1/0.05) * log2(e)
#define C2 (-28.853900817779268f)

constexpr int CHUNKS = 64;                     // row chunks per batch
constexpr int ROWS_PER_CHUNK = N / CHUNKS;     // 32

__device__ __forceinline__ unsigned short f2bf(float f) {
  union { float f; unsigned u; } x; x.f = f;
  unsigned r = x.u + 0x7fffu + ((x.u >> 16) & 1u);   // RNE; inputs finite positive
  return (unsigned short)(r >> 16);
}
__device__ __forceinline__ float bflo(unsigned w) { union { unsigned u; float f; } x; x.u = w << 16; return x.f; }
__device__ __forceinline__ float bfhi(unsigned w) { union { unsigned u; float f; } x; x.u = w & 0xffff0000u; return x.f; }

// ---------------- init: K = bf16(exp(-cost/eps)) ----------------
__global__ __launch_bounds__(256) void init_K(const float* __restrict__ cost,
                                              uint4* __restrict__ K) {
  unsigned gid = blockIdx.x * 256u + threadIdx.x;        // 4,194,304 threads x 16 elems
  const float4* c4 = (const float4*)cost;
  uint4 w0, w1;
  {
    float4 a = c4[(size_t)gid * 4 + 0];
    float4 b = c4[(size_t)gid * 4 + 1];
    w0.x = (unsigned)f2bf(exp2f(a.x * C2)) | ((unsigned)f2bf(exp2f(a.y * C2)) << 16);
    w0.y = (unsigned)f2bf(exp2f(a.z * C2)) | ((unsigned)f2bf(exp2f(a.w * C2)) << 16);
    w0.z = (unsigned)f2bf(exp2f(b.x * C2)) | ((unsigned)f2bf(exp2f(b.y * C2)) << 16);
    w0.w = (unsigned)f2bf(exp2f(b.z * C2)) | ((unsigned)f2bf(exp2f(b.w * C2)) << 16);
  }
  {
    float4 a = c4[(size_t)gid * 4 + 2];
    float4 b = c4[(size_t)gid * 4 + 3];
    w1.x = (unsigned)f2bf(exp2f(a.x * C2)) | ((unsigned)f2bf(exp2f(a.y * C2)) << 16);
    w1.y = (unsigned)f2bf(exp2f(a.z * C2)) | ((unsigned)f2bf(exp2f(a.w * C2)) << 16);
    w1.z = (unsigned)f2bf(exp2f(b.x * C2)) | ((unsigned)f2bf(exp2f(b.y * C2)) << 16);
    w1.w = (unsigned)f2bf(exp2f(b.z * C2)) | ((unsigned)f2bf(exp2f(b.w * C2)) << 16);
  }
  K[(size_t)gid * 2]     = w0;
  K[(size_t)gid * 2 + 1] = w1;
}

// ---------------- fused iteration kernel ----------------
// One WG per (chunk, b): 32 rows. Phase A: u[row] = (r+1e-12)/sum_m K[row,m]*v[m]
// (K from L3). Phase B: part[b,chunk,m] = sum_{rows} K[row,m]*u[row] (K from L2, hot).
template <bool FIRST>
__global__ __launch_bounds__(256) void iter_fused(const uint4* __restrict__ K,
                                                  const float* __restrict__ r,
                                                  const float* __restrict__ v,
                                                  float* __restrict__ u_out,
                                                  float* __restrict__ part) {
  const int b = blockIdx.y, chunk = blockIdx.x;
  const int n0 = chunk * ROWS_PER_CHUNK;
  const int t = threadIdx.x;
  __shared__ float vs[M];
  __shared__ float us[ROWS_PER_CHUNK];

  if (FIRST) {
    float4 one; one.x = one.y = one.z = one.w = 1.0f;
    ((float4*)vs)[t] = one;
    ((float4*)vs)[t + 256] = one;
  } else {
    const float4* vv = (const float4*)(v + (size_t)b * M);
    ((float4*)vs)[t]       = vv[t];
    ((float4*)vs)[t + 256] = vv[t + 256];
  }
  __syncthreads();

  const int wave = t >> 6, lane = t & 63;
  // Per-lane 32 v values in registers, reused across this wave's 8 rows.
  float vreg[32];
#pragma unroll
  for (int it = 0; it < 4; ++it) {
    float4 a = ((const float4*)vs)[it * 128 + lane * 2];
    float4 c = ((const float4*)vs)[it * 128 + lane * 2 + 1];
    vreg[it * 8 + 0] = a.x; vreg[it * 8 + 1] = a.y; vreg[it * 8 + 2] = a.z; vreg[it * 8 + 3] = a.w;
    vreg[it * 8 + 4] = c.x; vreg[it * 8 + 5] = c.y; vreg[it * 8 + 6] = c.z; vreg[it * 8 + 7] = c.w;
  }

  // Phase A: 8 rows per wave.
#pragma unroll
  for (int rr = 0; rr < ROWS_PER_CHUNK / 4; ++rr) {
    const int lrow = wave * (ROWS_PER_CHUNK / 4) + rr;
    const int row = n0 + lrow;
    const uint4* Kr = K + (size_t)(b * N + row) * (M / 8);
    float acc = 0.f;
#pragma unroll
    for (int it = 0; it < 4; ++it) {
      uint4 w = Kr[it * 64 + lane];
      acc += bflo(w.x) * vreg[it * 8 + 0] + bfhi(w.x) * vreg[it * 8 + 1]
           + bflo(w.y) * vreg[it * 8 + 2] + bfhi(w.y) * vreg[it * 8 + 3]
           + bflo(w.z) * vreg[it * 8 + 4] + bfhi(w.z) * vreg[it * 8 + 5]
           + bflo(w.w) * vreg[it * 8 + 6] + bfhi(w.w) * vreg[it * 8 + 7];
    }
#pragma unroll
    for (int off = 32; off; off >>= 1) acc += __shfl_xor(acc, off, 64);
    if (lane == 0) {
      float uval = (r[b * N + row] + 1e-12f) / acc;
      us[lrow] = uval;
      u_out[b * N + row] = uval;
    }
  }
  __syncthreads();

  // Phase B: column partials over the same 32 rows (L2-hot).
  float acc8[8] = {0, 0, 0, 0, 0, 0, 0, 0};
  const uint4* Kb = K + (size_t)(b * N + n0) * (M / 8) + t;
#pragma unroll 8
  for (int n = 0; n < ROWS_PER_CHUNK; ++n) {
    uint4 w = Kb[(size_t)n * (M / 8)];
    float uval = us[n];
    acc8[0] += bflo(w.x) * uval; acc8[1] += bfhi(w.x) * uval;
    acc8[2] += bflo(w.y) * uval; acc8[3] += bfhi(w.y) * uval;
    acc8[4] += bflo(w.z) * uval; acc8[5] += bfhi(w.z) * uval;
    acc8[6] += bflo(w.w) * uval; acc8[7] += bfhi(w.w) * uval;
  }
  float4* P = (float4*)(part + (size_t)(b * CHUNKS + chunk) * M) + t * 2;
  float4 o0; o0.x = acc8[0]; o0.y = acc8[1]; o0.z = acc8[2]; o0.w = acc8[3];
  float4 o1; o1.x = acc8[4]; o1.y = acc8[5]; o1.z = acc8[6]; o1.w = acc8[7];
  P[0] = o0; P[1] = o1;
}

// ---------------- v-finalize: v[b,m] = (c[b,m]+1e-12) / sum_chunks partial ----------------
__global__ __launch_bounds__(256) void v_fin(const float* __restrict__ part,
                                             const float* __restrict__ c,
                                             float* __restrict__ v) {
  const int g = blockIdx.x * 256 + threadIdx.x;   // 0..B*M-1
  const int b = g >> 11, m = g & (M - 1);
  float s = 0.f;
#pragma unroll 8
  for (int ch = 0; ch < CHUNKS; ++ch) s += part[(size_t)(b * CHUNKS + ch) * M + m];
  v[g] = (c[g] + 1e-12f) / s;
}

// ---------------- final: T = u[n] * exp(-cost/eps) * v[m], exact from fp32 cost ----------------
__global__ __launch_bounds__(256) void final_T(const float* __restrict__ cost,
                                               const float* __restrict__ u,
                                               const float* __restrict__ v,
                                               float* __restrict__ out) {
  const int b = blockIdx.z, n = blockIdx.y;
  const int m4 = blockIdx.x * 256 + threadIdx.x;  // 0..M/4-1
  const float un = u[b * N + n];
  float4 vv = ((const float4*)(v + (size_t)b * M))[m4];
  const size_t off = ((size_t)(b * N + n) * M) / 4 + m4;
  float4 cc = ((const float4*)cost)[off];
  float4 o;
  o.x = un * vv.x * exp2f(cc.x * C2);
  o.y = un * vv.y * exp2f(cc.y * C2);
  o.z = un * vv.z * exp2f(cc.z * C2);
  o.w = un * vv.w * exp2f(cc.w * C2);
  ((float4*)out)[off] = o;
}

// ---------------- fallback (ws too small for K): stream fp32 cost ----------------
__global__ __launch_bounds__(256) void init_v_only(float* __restrict__ v) {
  unsigned g = blockIdx.x * 256u + threadIdx.x;
  if (g < (unsigned)(B * M)) v[g] = 1.0f;
}

template <bool FIRST>
__global__ __launch_bounds__(256) void iter_fused_cost(const float* __restrict__ cost,
                                                       const float* __restrict__ r,
                                                       const float* __restrict__ v,
                                                       float* __restrict__ u_out,
                                                       float* __restrict__ part) {
  const int b = blockIdx.y, chunk = blockIdx.x;
  const int n0 = chunk * ROWS_PER_CHUNK;
  const int t = threadIdx.x;
  __shared__ float vs[M];
  __shared__ float us[ROWS_PER_CHUNK];
  if (FIRST) {
    float4 one; one.x = one.y = one.z = one.w = 1.0f;
    ((float4*)vs)[t] = one; ((float4*)vs)[t + 256] = one;
  } else {
    const float4* vv = (const float4*)(v + (size_t)b * M);
    ((float4*)vs)[t] = vv[t]; ((float4*)vs)[t + 256] = vv[t + 256];
  }
  __syncthreads();
  const int wave = t >> 6, lane = t & 63;
  float vreg[32];
#pragma unroll
  for (int it = 0; it < 4; ++it) {
    float4 a = ((const float4*)vs)[it * 128 + lane * 2];
    float4 c = ((const float4*)vs)[it * 128 + lane * 2 + 1];
    vreg[it * 8 + 0] = a.x; vreg[it * 8 + 1] = a.y; vreg[it * 8 + 2] = a.z; vreg[it * 8 + 3] = a.w;
    vreg[it * 8 + 4] = c.x; vreg[it * 8 + 5] = c.y; vreg[it * 8 + 6] = c.z; vreg[it * 8 + 7] = c.w;
  }
#pragma unroll
  for (int rr = 0; rr < ROWS_PER_CHUNK / 4; ++rr) {
    const int lrow = wave * (ROWS_PER_CHUNK / 4) + rr;
    const int row = n0 + lrow;
    const float4* Cr = (const float4*)(cost + (size_t)(b * N + row) * M);
    float acc = 0.f;
#pragma unroll
    for (int it = 0; it < 4; ++it) {
      float4 a = Cr[it * 128 + lane * 2];
      float4 c = Cr[it * 128 + lane * 2 + 1];
      acc += exp2f(a.x * C2) * vreg[it * 8 + 0] + exp2f(a.y * C2) * vreg[it * 8 + 1]
           + exp2f(a.z * C2) * vreg[it * 8 + 2] + exp2f(a.w * C2) * vreg[it * 8 + 3]
           + exp2f(c.x * C2) * vreg[it * 8 + 4] + exp2f(c.y * C2) * vreg[it * 8 + 5]
           + exp2f(c.z * C2) * vreg[it * 8 + 6] + exp2f(c.w * C2) * vreg[it * 8 + 7];
    }
#pragma unroll
    for (int off = 32; off; off >>= 1) acc += __shfl_xor(acc, off, 64);
    if (lane == 0) {
      float uval = (r[b * N + row] + 1e-12f) / acc;
      us[lrow] = uval;
      u_out[b * N + row] = uval;
    }
  }
  __syncthreads();
  float acc8[8] = {0, 0, 0, 0, 0, 0, 0, 0};
  const float4* Cb = (const float4*)(cost + (size_t)(b * N + n0) * M) + t * 2;
#pragma unroll 2
  for (int n = 0; n < ROWS_PER_CHUNK; ++n) {
    float4 a = Cb[(size_t)n * (M / 4)];
    float4 c = Cb[(size_t)n * (M / 4) + 1];
    float uval = us[n];
    acc8[0] += exp2f(a.x * C2) * uval; acc8[1] += exp2f(a.y * C2) * uval;
    acc8[2] += exp2f(a.z * C2) * uval; acc8[3] += exp2f(a.w * C2) * uval;
    acc8[4] += exp2f(c.x * C2) * uval; acc8[5] += exp2f(c.y * C2) * uval;
    acc8[6] += exp2f(c.z * C2) * uval; acc8[7] += exp2f(c.w * C2) * uval;
  }
  float4* P = (float4*)(part + (size_t)(b * CHUNKS + chunk) * M) + t * 2;
  float4 o0; o0.x = acc8[0]; o0.y = acc8[1]; o0.z = acc8[2]; o0.w = acc8[3];
  float4 o1; o1.x = acc8[4]; o1.y = acc8[5]; o1.z = acc8[6]; o1.w = acc8[7];
  P[0] = o0; P[1] = o1;
}

extern "C" void kernel_launch(void* const* d_in, const int* in_sizes, int n_in,
                              void* d_out, int out_size, void* d_ws, size_t ws_size,
                              hipStream_t stream) {
  const float* cost = (const float*)d_in[0];
  const float* r    = (const float*)d_in[1];
  const float* c    = (const float*)d_in[2];
  float* out        = (float*)d_out;
  char* ws          = (char*)d_ws;

  const size_t K_bytes    = (size_t)B * N * M * 2;           // 128 MiB bf16 K
  const size_t u_bytes    = (size_t)B * N * 4;
  const size_t v_bytes    = (size_t)B * M * 4;
  const size_t part_bytes = (size_t)B * CHUNKS * M * 4;      // 8 MiB
  const size_t need_main  = K_bytes + u_bytes + v_bytes + part_bytes;
  const bool useK = (ws_size >= need_main);                  // ws_size constant across calls

  uint4* K; float *u, *v, *part;
  if (useK) {
    K = (uint4*)ws;
    u = (float*)(ws + K_bytes);
  } else {
    K = nullptr;
    u = (float*)ws;
  }
  v = u + (size_t)B * N;
  part = v + (size_t)B * M;

  if (useK) {
    init_K<<<dim3((B * (size_t)N * M) / (256 * 16)), 256, 0, stream>>>(cost, K);
    iter_fused<true><<<dim3(CHUNKS, B), 256, 0, stream>>>(K, r, v, u, part);
    v_fin<<<dim3(B * M / 256), 256, 0, stream>>>(part, c, v);
    for (int it = 1; it < MAX_ITER; ++it) {
      iter_fused<false><<<dim3(CHUNKS, B), 256, 0, stream>>>(K, r, v, u, part);
      v_fin<<<dim3(B * M / 256), 256, 0, stream>>>(part, c, v);
    }
  } else {
    iter_fused_cost<true><<<dim3(CHUNKS, B), 256, 0, stream>>>(cost, r, v, u, part);
    v_fin<<<dim3(B * M / 256), 256, 0, stream>>>(part, c, v);
    for (int it = 1; it < MAX_ITER; ++it) {
      iter_fused_cost<false><<<dim3(CHUNKS, B), 256, 0, stream>>>(cost, r, v, u, part);
      v_fin<<<dim3(B * M / 256), 256, 0, stream>>>(part, c, v);
    }
  }

  final_T<<<dim3(M / 1024, N, B), 256, 0, stream>>>(cost, u, v, out);
}